// Round 1
// baseline (617.206 us; speedup 1.0000x reference)
//
#include <hip/hip_runtime.h>
#include <hip/hip_bf16.h>
#include <math.h>

// Problem constants
#define B_TOK 4096
#define NE 16
#define DI 1024
#define DH 2048
#define DOUT 1024
#define NSLOT (B_TOK * 2)   // 8192 (token, expert) assignments, exactly

typedef unsigned short u16;
typedef short bfrag __attribute__((ext_vector_type(8)));   // 8 bf16 input frag (4 VGPRs)
typedef float f32x4 __attribute__((ext_vector_type(4)));   // MFMA accumulator
typedef u16 u16x8 __attribute__((ext_vector_type(8)));

// ---------- helpers ----------
__device__ __forceinline__ u16 f2bf(float f) {   // fp32 -> bf16 round-to-nearest-even
    union { float f; unsigned u; } v; v.f = f;
    return (u16)((v.u + 0x7fffu + ((v.u >> 16) & 1u)) >> 16);
}

// async 16B/lane global->LDS. LDS dest must be wave-uniform base (+lane*16 by HW).
__device__ __forceinline__ void async16(const void* g, void* lds) {
    __builtin_amdgcn_global_load_lds(
        (const __attribute__((address_space(1))) void*)g,
        (__attribute__((address_space(3))) void*)lds,
        16, 0, 0);
}

// ---------- kernel 0: zero output + counts ----------
__global__ void zero_init(float* __restrict__ out, int n4, int* __restrict__ counts) {
    int i = blockIdx.x * blockDim.x + threadIdx.x;
    if (i < n4) ((float4*)out)[i] = make_float4(0.f, 0.f, 0.f, 0.f);
    if (blockIdx.x == 0 && threadIdx.x < NE) counts[threadIdx.x] = 0;
}

// ---------- kernel 1: fp32 -> bf16 convert, 8 elems/thread ----------
__global__ void convert_bf16(const float* __restrict__ src, u16* __restrict__ dst, int n8) {
    int i = blockIdx.x * blockDim.x + threadIdx.x;
    if (i >= n8) return;
    const float4* s4 = (const float4*)src;
    float4 a = s4[2 * i], b = s4[2 * i + 1];
    u16x8 r;
    r[0] = f2bf(a.x); r[1] = f2bf(a.y); r[2] = f2bf(a.z); r[3] = f2bf(a.w);
    r[4] = f2bf(b.x); r[5] = f2bf(b.y); r[6] = f2bf(b.z); r[7] = f2bf(b.w);
    ((u16x8*)dst)[i] = r;
}

// ---------- kernel 2: gating (fp64 for exact top-k ordering) ----------
__global__ __launch_bounds__(256) void gate_topk(
    const float* __restrict__ x, const float* __restrict__ gw,
    int* __restrict__ token_e, float* __restrict__ token_w, int* __restrict__ counts)
{
    int wave = threadIdx.x >> 6, lane = threadIdx.x & 63;
    int t = blockIdx.x * 4 + wave;            // grid 1024 * 4 waves = 4096 tokens
    const float4* x4 = (const float4*)(x + (size_t)t * DI);
    const float4* g4 = (const float4*)gw;
    double acc[NE];
#pragma unroll
    for (int e = 0; e < NE; ++e) acc[e] = 0.0;
#pragma unroll
    for (int i = 0; i < 4; ++i) {
        float4 xv = x4[lane + i * 64];
#pragma unroll
        for (int e = 0; e < NE; ++e) {
            float4 gv = g4[e * 256 + lane + i * 64];
            acc[e] += (double)xv.x * gv.x + (double)xv.y * gv.y
                    + (double)xv.z * gv.z + (double)xv.w * gv.w;
        }
    }
#pragma unroll
    for (int e = 0; e < NE; ++e) {
        double v = acc[e];
        for (int off = 32; off; off >>= 1) v += __shfl_xor(v, off, 64);
        acc[e] = v;
    }
    if (lane == 0) {
        int e0 = 0; double v0 = acc[0];
#pragma unroll
        for (int e = 1; e < NE; ++e) if (acc[e] > v0) { v0 = acc[e]; e0 = e; }
        int e1 = -1; double v1 = -1e300;
#pragma unroll
        for (int e = 0; e < NE; ++e) if (e != e0 && acc[e] > v1) { v1 = acc[e]; e1 = e; }
        double d = exp(v1 - v0);                 // v1 <= v0
        float w0 = (float)(1.0 / (1.0 + d));
        float w1 = (float)(d / (1.0 + d));
        token_e[2 * t] = e0; token_e[2 * t + 1] = e1;
        token_w[2 * t] = w0; token_w[2 * t + 1] = w1;
        atomicAdd(&counts[e0], 1); atomicAdd(&counts[e1], 1);
    }
}

// ---------- kernel 3: serial 16-entry exclusive scan ----------
__global__ void scan_offsets(const int* __restrict__ counts,
                             int* __restrict__ offsets, int* __restrict__ cursor) {
    if (blockIdx.x == 0 && threadIdx.x == 0) {
        int s = 0;
        for (int e = 0; e < NE; ++e) { offsets[e] = s; cursor[e] = s; s += counts[e]; }
    }
}

// ---------- kernel 4: fill per-expert slot lists ----------
__global__ void fill_slots(const int* __restrict__ token_e, const float* __restrict__ token_w,
                           int* __restrict__ cursor, int* __restrict__ slot_token,
                           float* __restrict__ slot_wgt) {
    int t = blockIdx.x * blockDim.x + threadIdx.x;
    if (t >= B_TOK) return;
#pragma unroll
    for (int k = 0; k < 2; ++k) {
        int e = token_e[2 * t + k];
        int pos = atomicAdd(&cursor[e], 1);
        slot_token[pos] = t;
        slot_wgt[pos] = token_w[2 * t + k];
    }
}

// ---------- grouped GEMM: 128x128 tile, BK=32, 4 waves (2x2), 16x16x32 bf16 MFMA ----------
// PHASE 1: h = relu(x_sel @ w1[e]^T + b1[e]) -> hb (bf16)
// PHASE 2: out[token] += wgt * (h @ w2[e]^T + b2[e])  (fp32 atomics)
template <int PHASE>
__global__ __launch_bounds__(256) void moe_gemm(
    const u16* __restrict__ Abuf,   // PHASE1: xb [4096][1024]; PHASE2: hb [8192][2048]
    const u16* __restrict__ Bbuf,   // bf16 weights: [NE][NDIM][KDIM] (K contiguous)
    const float* __restrict__ bias, // [NE][NDIM] fp32
    const int* __restrict__ counts, const int* __restrict__ offsets,
    const int* __restrict__ slot_token, const float* __restrict__ slot_wgt,
    u16* __restrict__ hb, float* __restrict__ out)
{
    constexpr int KDIM = (PHASE == 1) ? DI : DH;
    constexpr int NDIM = (PHASE == 1) ? DH : DOUT;

    const int e = blockIdx.z;
    const int cnt = counts[e];
    const int m0 = blockIdx.y * 128;
    if (m0 >= cnt) return;                    // wave-uniform early exit
    const int n0 = blockIdx.x * 128;
    const int sbase = offsets[e];

    __shared__ u16 ldsbuf[8192];              // 16 KB: A tile [128][32] | B tile [128][32]
    u16* alds = ldsbuf;
    u16* blds = ldsbuf + 4096;

    const int tid = threadIdx.x;
    const int wv = tid >> 6, lane = tid & 63;
    const int lrow = lane >> 2, lkc = lane & 3;  // staging: row-within-16, 16B k-chunk

    // staging rows for the two rounds (this wave covers rows wv*16.. and 64+wv*16..)
    const int arow0 = wv * 16 + lrow;
    const int arow1 = 64 + wv * 16 + lrow;

    const u16* aptr0; const u16* aptr1;
    if (PHASE == 1) {
        int c = cnt - 1;
        int r0 = m0 + arow0; if (r0 > c) r0 = c;
        int r1 = m0 + arow1; if (r1 > c) r1 = c;
        aptr0 = Abuf + (size_t)slot_token[sbase + r0] * KDIM + lkc * 8;
        aptr1 = Abuf + (size_t)slot_token[sbase + r1] * KDIM + lkc * 8;
    } else {
        int s0 = sbase + m0 + arow0; if (s0 > NSLOT - 1) s0 = NSLOT - 1;
        int s1 = sbase + m0 + arow1; if (s1 > NSLOT - 1) s1 = NSLOT - 1;
        aptr0 = Abuf + (size_t)s0 * KDIM + lkc * 8;
        aptr1 = Abuf + (size_t)s1 * KDIM + lkc * 8;
    }
    const u16* bbase = Bbuf + (size_t)e * NDIM * KDIM;
    const u16* bptr0 = bbase + (size_t)(n0 + arow0) * KDIM + lkc * 8;
    const u16* bptr1 = bbase + (size_t)(n0 + arow1) * KDIM + lkc * 8;

    // wave-uniform LDS destinations (HW adds lane*16 bytes)
    u16* alds_w0 = alds + wv * 512;           // round 0: bytes [wv*1024 ..]
    u16* alds_w1 = alds + 2048 + wv * 512;    // round 1: bytes [4096 + wv*1024 ..]
    u16* blds_w0 = blds + wv * 512;
    u16* blds_w1 = blds + 2048 + wv * 512;

    f32x4 acc[4][4];
#pragma unroll
    for (int i = 0; i < 4; ++i)
#pragma unroll
        for (int j = 0; j < 4; ++j) acc[i][j] = (f32x4){0.f, 0.f, 0.f, 0.f};

    const int wm = (wv & 1) * 64, wn = (wv >> 1) * 64;   // 2x2 wave grid, 64x64 per wave
    const int quad = lane >> 4, mr = lane & 15;
    const int aoff = (wm + mr) * 32 + quad * 8;          // u16 units; row stride 32
    const int boff = (wn + mr) * 32 + quad * 8;

    const int nk = KDIM / 32;
    for (int kt = 0; kt < nk; ++kt) {
        __syncthreads();                       // prev tile fully consumed
        async16(aptr0 + kt * 32, alds_w0);
        async16(aptr1 + kt * 32, alds_w1);
        async16(bptr0 + kt * 32, blds_w0);
        async16(bptr1 + kt * 32, blds_w1);
        __syncthreads();                       // vmcnt(0) drain -> tile visible
        bfrag af[4], bf[4];
#pragma unroll
        for (int i = 0; i < 4; ++i) af[i] = *(const bfrag*)(alds + aoff + i * 512);
#pragma unroll
        for (int j = 0; j < 4; ++j) bf[j] = *(const bfrag*)(blds + boff + j * 512);
#pragma unroll
        for (int i = 0; i < 4; ++i)
#pragma unroll
            for (int j = 0; j < 4; ++j)
                acc[i][j] = __builtin_amdgcn_mfma_f32_16x16x32_bf16(af[i], bf[j], acc[i][j], 0, 0, 0);
    }

    // epilogue. C/D layout: n = lane&15, m = quad*4 + reg  [m89-verified]
    const float* bias_e = bias + e * NDIM;
    if constexpr (PHASE == 1) {
#pragma unroll
        for (int i = 0; i < 4; ++i) {
            int mbase = wm + i * 16 + quad * 4;
#pragma unroll
            for (int j = 0; j < 4; ++j) {
                int n = n0 + wn + j * 16 + mr;
                float bv = bias_e[n];
#pragma unroll
                for (int r = 0; r < 4; ++r) {
                    int m = m0 + mbase + r;
                    if (m < cnt) {
                        float v = acc[i][j][r] + bv;
                        v = v > 0.f ? v : 0.f;
                        hb[(size_t)(sbase + m) * DH + n] = f2bf(v);
                    }
                }
            }
        }
    } else {
#pragma unroll
        for (int i = 0; i < 4; ++i) {
            int mbase = wm + i * 16 + quad * 4;
#pragma unroll
            for (int r = 0; r < 4; ++r) {
                int m = m0 + mbase + r;
                if (m < cnt) {
                    int slot = sbase + m;
                    int tok = slot_token[slot];
                    float wgt = slot_wgt[slot];
                    float* orow = out + (size_t)tok * DOUT + n0 + wn;
#pragma unroll
                    for (int j = 0; j < 4; ++j) {
                        int nl = j * 16 + mr;
                        float v = wgt * (acc[i][j][r] + bias_e[n0 + wn + nl]);
                        atomicAdd(orow + nl, v);
                    }
                }
            }
        }
    }
}

// ---------- launch ----------
extern "C" void kernel_launch(void* const* d_in, const int* in_sizes, int n_in,
                              void* d_out, int out_size, void* d_ws, size_t ws_size,
                              hipStream_t stream) {
    const float* x  = (const float*)d_in[0];   // [4096][1024]
    const float* gw = (const float*)d_in[1];   // [16][1024]
    const float* w1 = (const float*)d_in[2];   // [16][2048][1024]
    const float* b1 = (const float*)d_in[3];   // [16][2048]
    const float* w2 = (const float*)d_in[4];   // [16][1024][2048]
    const float* b2 = (const float*)d_in[5];   // [16][1024]
    float* out = (float*)d_out;                // [4096][1024] fp32

    // workspace layout (~104.1 MiB)
    char* ws = (char*)d_ws;
    u16* xb = (u16*)ws;                                   //  8,388,608 B
    u16* wb = (u16*)(ws + 8388608);                       // 67,108,864 B (w1 then reused for w2)
    u16* hb = (u16*)(ws + 8388608 + 67108864);            // 33,554,432 B
    char* rb = ws + 109051904;
    int*   counts     = (int*)(rb);
    int*   offsets    = (int*)(rb + 64);
    int*   cursor     = (int*)(rb + 128);
    int*   token_e    = (int*)(rb + 192);
    float* token_w    = (float*)(rb + 192 + 32768);
    int*   slot_token = (int*)(rb + 192 + 65536);
    float* slot_wgt   = (float*)(rb + 192 + 98304);

    zero_init<<<4096, 256, 0, stream>>>(out, (B_TOK * DOUT) / 4, counts);
    convert_bf16<<<2048, 256, 0, stream>>>(x, xb, (B_TOK * DI) / 8);
    convert_bf16<<<16384, 256, 0, stream>>>(w1, wb, (NE * DH * DI) / 8);
    gate_topk<<<1024, 256, 0, stream>>>(x, gw, token_e, token_w, counts);
    scan_offsets<<<1, 64, 0, stream>>>(counts, offsets, cursor);
    fill_slots<<<16, 256, 0, stream>>>(token_e, token_w, cursor, slot_token, slot_wgt);
    moe_gemm<1><<<dim3(DH / 128, B_TOK / 128, NE), 256, 0, stream>>>(
        xb, wb, b1, counts, offsets, slot_token, slot_wgt, hb, out);
    convert_bf16<<<16384, 256, 0, stream>>>(w2, wb, (NE * DOUT * DH) / 8);
    moe_gemm<2><<<dim3(DOUT / 128, B_TOK / 128, NE), 256, 0, stream>>>(
        hb, wb, b2, counts, offsets, slot_token, slot_wgt, hb, out);
}

// Round 2
// 515.122 us; speedup vs baseline: 1.1982x; 1.1982x over previous
//
#include <hip/hip_runtime.h>
#include <hip/hip_bf16.h>
#include <math.h>

// Problem constants
#define B_TOK 4096
#define NE 16
#define DI 1024
#define DH 2048
#define DOUT 1024
#define NSLOT (B_TOK * 2)   // 8192 (token, expert) assignments, exactly

typedef unsigned short u16;
typedef short bfrag __attribute__((ext_vector_type(8)));   // 8 bf16 input frag (4 VGPRs)
typedef float f32x4 __attribute__((ext_vector_type(4)));   // MFMA accumulator
typedef u16 u16x8 __attribute__((ext_vector_type(8)));

// ---------- helpers ----------
__device__ __forceinline__ u16 f2bf(float f) {   // fp32 -> bf16 round-to-nearest-even
    union { float f; unsigned u; } v; v.f = f;
    return (u16)((v.u + 0x7fffu + ((v.u >> 16) & 1u)) >> 16);
}

// async 16B/lane global->LDS. LDS dest must be wave-uniform base (+lane*16 by HW).
__device__ __forceinline__ void async16(const void* g, void* lds) {
    __builtin_amdgcn_global_load_lds(
        (const __attribute__((address_space(1))) void*)g,
        (__attribute__((address_space(3))) void*)lds,
        16, 0, 0);
}

// ---------- kernel 0: zero output ----------
__global__ void zero_init(float* __restrict__ out, int n4) {
    int i = blockIdx.x * blockDim.x + threadIdx.x;
    if (i < n4) ((float4*)out)[i] = make_float4(0.f, 0.f, 0.f, 0.f);
}

// ---------- kernel 1: fp32 -> bf16 convert, 8 elems/thread ----------
__global__ void convert_bf16(const float* __restrict__ src, u16* __restrict__ dst, int n8) {
    int i = blockIdx.x * blockDim.x + threadIdx.x;
    if (i >= n8) return;
    const float4* s4 = (const float4*)src;
    float4 a = s4[2 * i], b = s4[2 * i + 1];
    u16x8 r;
    r[0] = f2bf(a.x); r[1] = f2bf(a.y); r[2] = f2bf(a.z); r[3] = f2bf(a.w);
    r[4] = f2bf(b.x); r[5] = f2bf(b.y); r[6] = f2bf(b.z); r[7] = f2bf(b.w);
    ((u16x8*)dst)[i] = r;
}

// ---------- kernel 2: gating (fp64 dots for exact top-k ordering; NO global atomics) ----------
__global__ __launch_bounds__(256) void gate_topk(
    const float* __restrict__ x, const float* __restrict__ gw,
    int* __restrict__ token_e, float* __restrict__ token_w)
{
    int wave = threadIdx.x >> 6, lane = threadIdx.x & 63;
    int t = blockIdx.x * 4 + wave;            // grid 1024 * 4 waves = 4096 tokens
    const float4* x4 = (const float4*)(x + (size_t)t * DI);
    const float4* g4 = (const float4*)gw;
    double acc[NE];
#pragma unroll
    for (int e = 0; e < NE; ++e) acc[e] = 0.0;
#pragma unroll
    for (int i = 0; i < 4; ++i) {
        float4 xv = x4[lane + i * 64];
#pragma unroll
        for (int e = 0; e < NE; ++e) {
            float4 gv = g4[e * 256 + lane + i * 64];
            acc[e] += (double)xv.x * gv.x + (double)xv.y * gv.y
                    + (double)xv.z * gv.z + (double)xv.w * gv.w;
        }
    }
#pragma unroll
    for (int e = 0; e < NE; ++e) {
        double v = acc[e];
        for (int off = 32; off; off >>= 1) v += __shfl_xor(v, off, 64);
        acc[e] = v;
    }
    if (lane == 0) {
        int e0 = 0; double v0 = acc[0];
#pragma unroll
        for (int e = 1; e < NE; ++e) if (acc[e] > v0) { v0 = acc[e]; e0 = e; }
        int e1 = -1; double v1 = -1e300;
#pragma unroll
        for (int e = 0; e < NE; ++e) if (e != e0 && acc[e] > v1) { v1 = acc[e]; e1 = e; }
        float d = expf((float)(v1 - v0));        // v1 <= v0, d in (0,1]
        float w0 = 1.f / (1.f + d);
        float w1 = d * w0;
        token_e[2 * t] = e0; token_e[2 * t + 1] = e1;
        token_w[2 * t] = w0; token_w[2 * t + 1] = w1;
    }
}

// ---------- kernel 3: routing — histogram + scan + slot fill, one block, LDS atomics ----------
__global__ __launch_bounds__(1024) void route(
    const int* __restrict__ token_e, const float* __restrict__ token_w,
    int* __restrict__ counts, int* __restrict__ offsets,
    int* __restrict__ slot_token, float* __restrict__ slot_wgt)
{
    __shared__ int lcnt[NE];
    __shared__ int lcur[NE];
    int tid = threadIdx.x;
    if (tid < NE) lcnt[tid] = 0;
    __syncthreads();
    for (int i = tid; i < NSLOT; i += 1024) atomicAdd(&lcnt[token_e[i]], 1);
    __syncthreads();
    if (tid == 0) {
        int s = 0;
        for (int e = 0; e < NE; ++e) {
            int c = lcnt[e];
            counts[e] = c; offsets[e] = s; lcur[e] = s; s += c;
        }
    }
    __syncthreads();
    for (int i = tid; i < NSLOT; i += 1024) {
        int e = token_e[i];
        int pos = atomicAdd(&lcur[e], 1);
        slot_token[pos] = i >> 1;
        slot_wgt[pos] = token_w[i];
    }
}

// ---------- grouped GEMM: 128x128 tile, BK=32, 4 waves (2x2), 16x16x32 bf16 MFMA ----------
// PHASE 1: h = relu(x_sel @ w1[e]^T + b1[e]) -> hb (bf16)
// PHASE 2: out[token] += wgt * (h @ w2[e]^T + b2[e])  (fp32 atomics)
template <int PHASE>
__global__ __launch_bounds__(256) void moe_gemm(
    const u16* __restrict__ Abuf,   // PHASE1: xb [4096][1024]; PHASE2: hb [8192][2048]
    const u16* __restrict__ Bbuf,   // bf16 weights: [NE][NDIM][KDIM] (K contiguous)
    const float* __restrict__ bias, // [NE][NDIM] fp32
    const int* __restrict__ counts, const int* __restrict__ offsets,
    const int* __restrict__ slot_token, const float* __restrict__ slot_wgt,
    u16* __restrict__ hb, float* __restrict__ out)
{
    constexpr int KDIM = (PHASE == 1) ? DI : DH;
    constexpr int NDIM = (PHASE == 1) ? DH : DOUT;

    const int e = blockIdx.z;
    const int cnt = counts[e];
    const int m0 = blockIdx.y * 128;
    if (m0 >= cnt) return;                    // wave-uniform early exit
    const int n0 = blockIdx.x * 128;
    const int sbase = offsets[e];

    __shared__ u16 ldsbuf[8192];              // 16 KB: A tile [128][32] | B tile [128][32]
    u16* alds = ldsbuf;
    u16* blds = ldsbuf + 4096;

    const int tid = threadIdx.x;
    const int wv = tid >> 6, lane = tid & 63;
    const int lrow = lane >> 2, lkc = lane & 3;  // staging: row-within-16, 16B k-chunk

    // staging rows for the two rounds (this wave covers rows wv*16.. and 64+wv*16..)
    const int arow0 = wv * 16 + lrow;
    const int arow1 = 64 + wv * 16 + lrow;

    const u16* aptr0; const u16* aptr1;
    if (PHASE == 1) {
        int c = cnt - 1;
        int r0 = m0 + arow0; if (r0 > c) r0 = c;
        int r1 = m0 + arow1; if (r1 > c) r1 = c;
        aptr0 = Abuf + (size_t)slot_token[sbase + r0] * KDIM + lkc * 8;
        aptr1 = Abuf + (size_t)slot_token[sbase + r1] * KDIM + lkc * 8;
    } else {
        int s0 = sbase + m0 + arow0; if (s0 > NSLOT - 1) s0 = NSLOT - 1;
        int s1 = sbase + m0 + arow1; if (s1 > NSLOT - 1) s1 = NSLOT - 1;
        aptr0 = Abuf + (size_t)s0 * KDIM + lkc * 8;
        aptr1 = Abuf + (size_t)s1 * KDIM + lkc * 8;
    }
    const u16* bbase = Bbuf + (size_t)e * NDIM * KDIM;
    const u16* bptr0 = bbase + (size_t)(n0 + arow0) * KDIM + lkc * 8;
    const u16* bptr1 = bbase + (size_t)(n0 + arow1) * KDIM + lkc * 8;

    // wave-uniform LDS destinations (HW adds lane*16 bytes)
    u16* alds_w0 = alds + wv * 512;           // round 0: bytes [wv*1024 ..]
    u16* alds_w1 = alds + 2048 + wv * 512;    // round 1: bytes [4096 + wv*1024 ..]
    u16* blds_w0 = blds + wv * 512;
    u16* blds_w1 = blds + 2048 + wv * 512;

    f32x4 acc[4][4];
#pragma unroll
    for (int i = 0; i < 4; ++i)
#pragma unroll
        for (int j = 0; j < 4; ++j) acc[i][j] = (f32x4){0.f, 0.f, 0.f, 0.f};

    const int wm = (wv & 1) * 64, wn = (wv >> 1) * 64;   // 2x2 wave grid, 64x64 per wave
    const int quad = lane >> 4, mr = lane & 15;
    const int aoff = (wm + mr) * 32 + quad * 8;          // u16 units; row stride 32
    const int boff = (wn + mr) * 32 + quad * 8;

    const int nk = KDIM / 32;
    for (int kt = 0; kt < nk; ++kt) {
        __syncthreads();                       // prev tile fully consumed
        async16(aptr0 + kt * 32, alds_w0);
        async16(aptr1 + kt * 32, alds_w1);
        async16(bptr0 + kt * 32, blds_w0);
        async16(bptr1 + kt * 32, blds_w1);
        __syncthreads();                       // vmcnt(0) drain -> tile visible
        bfrag af[4], bf[4];
#pragma unroll
        for (int i = 0; i < 4; ++i) af[i] = *(const bfrag*)(alds + aoff + i * 512);
#pragma unroll
        for (int j = 0; j < 4; ++j) bf[j] = *(const bfrag*)(blds + boff + j * 512);
#pragma unroll
        for (int i = 0; i < 4; ++i)
#pragma unroll
            for (int j = 0; j < 4; ++j)
                acc[i][j] = __builtin_amdgcn_mfma_f32_16x16x32_bf16(af[i], bf[j], acc[i][j], 0, 0, 0);
    }

    // epilogue. C/D layout: n = lane&15, m = quad*4 + reg  [m89-verified]
    const float* bias_e = bias + e * NDIM;
    if constexpr (PHASE == 1) {
#pragma unroll
        for (int i = 0; i < 4; ++i) {
            int mbase = wm + i * 16 + quad * 4;
#pragma unroll
            for (int j = 0; j < 4; ++j) {
                int n = n0 + wn + j * 16 + mr;
                float bv = bias_e[n];
#pragma unroll
                for (int r = 0; r < 4; ++r) {
                    int m = m0 + mbase + r;
                    if (m < cnt) {
                        float v = acc[i][j][r] + bv;
                        v = v > 0.f ? v : 0.f;
                        hb[(size_t)(sbase + m) * DH + n] = f2bf(v);
                    }
                }
            }
        }
    } else {
#pragma unroll
        for (int i = 0; i < 4; ++i) {
            int mbase = wm + i * 16 + quad * 4;
#pragma unroll
            for (int r = 0; r < 4; ++r) {
                int m = m0 + mbase + r;
                if (m < cnt) {
                    int slot = sbase + m;
                    int tok = slot_token[slot];
                    float wgt = slot_wgt[slot];
                    float* orow = out + (size_t)tok * DOUT + n0 + wn;
#pragma unroll
                    for (int j = 0; j < 4; ++j) {
                        int nl = j * 16 + mr;
                        float v = wgt * (acc[i][j][r] + bias_e[n0 + wn + nl]);
                        atomicAdd(orow + nl, v);
                    }
                }
            }
        }
    }
}

// ---------- launch ----------
extern "C" void kernel_launch(void* const* d_in, const int* in_sizes, int n_in,
                              void* d_out, int out_size, void* d_ws, size_t ws_size,
                              hipStream_t stream) {
    const float* x  = (const float*)d_in[0];   // [4096][1024]
    const float* gw = (const float*)d_in[1];   // [16][1024]
    const float* w1 = (const float*)d_in[2];   // [16][2048][1024]
    const float* b1 = (const float*)d_in[3];   // [16][2048]
    const float* w2 = (const float*)d_in[4];   // [16][1024][2048]
    const float* b2 = (const float*)d_in[5];   // [16][1024]
    float* out = (float*)d_out;                // [4096][1024] fp32

    // workspace layout (~104.1 MiB)
    char* ws = (char*)d_ws;
    u16* xb = (u16*)ws;                                   //  8,388,608 B
    u16* wb = (u16*)(ws + 8388608);                       // 67,108,864 B (w1 then reused for w2)
    u16* hb = (u16*)(ws + 8388608 + 67108864);            // 33,554,432 B
    char* rb = ws + 109051904;
    int*   counts     = (int*)(rb);
    int*   offsets    = (int*)(rb + 64);
    int*   token_e    = (int*)(rb + 192);
    float* token_w    = (float*)(rb + 192 + 32768);
    int*   slot_token = (int*)(rb + 192 + 65536);
    float* slot_wgt   = (float*)(rb + 192 + 98304);

    zero_init<<<4096, 256, 0, stream>>>(out, (B_TOK * DOUT) / 4);
    convert_bf16<<<2048, 256, 0, stream>>>(x, xb, (B_TOK * DI) / 8);
    convert_bf16<<<16384, 256, 0, stream>>>(w1, wb, (NE * DH * DI) / 8);
    gate_topk<<<1024, 256, 0, stream>>>(x, gw, token_e, token_w);
    route<<<1, 1024, 0, stream>>>(token_e, token_w, counts, offsets, slot_token, slot_wgt);
    moe_gemm<1><<<dim3(DH / 128, B_TOK / 128, NE), 256, 0, stream>>>(
        xb, wb, b1, counts, offsets, slot_token, slot_wgt, hb, out);
    convert_bf16<<<16384, 256, 0, stream>>>(w2, wb, (NE * DOUT * DH) / 8);
    moe_gemm<2><<<dim3(DOUT / 128, B_TOK / 128, NE), 256, 0, stream>>>(
        hb, wb, b2, counts, offsets, slot_token, slot_wgt, hb, out);
}